// Round 9
// baseline (841.396 us; speedup 1.0000x reference)
//
#include <hip/hip_runtime.h>
#include <stdint.h>

#define T_TOK 8192
#define D_HID 1024
#define F_INT 4096
#define NEXP 8
#define NT2 (T_TOK*2)
#define BMR 256
#define NTIL 72              // max 256-row tiles: 16384/256 + 8
#define CBANKS 64

typedef __attribute__((ext_vector_type(4))) float f32x4;
typedef __attribute__((ext_vector_type(8))) __bf16 bf16x8;
typedef unsigned short u16;

__device__ __forceinline__ unsigned short f2bf(float x) {
  unsigned int u = __float_as_uint(x);
  u = u + 0x7FFFu + ((u >> 16) & 1u);
  return (unsigned short)(u >> 16);
}
__device__ __forceinline__ void gload_lds16(const void* g, void* l) {
  __builtin_amdgcn_global_load_lds(
      (const __attribute__((address_space(1))) unsigned int*)g,
      (__attribute__((address_space(3))) unsigned int*)l, 16, 0, 0);
}
__device__ __forceinline__ void wait_vm8() {
  asm volatile("s_waitcnt vmcnt(8)" ::: "memory");
  __builtin_amdgcn_sched_barrier(0);
}
__device__ __forceinline__ void wait_vm0() {
  asm volatile("s_waitcnt vmcnt(0)" ::: "memory");
  __builtin_amdgcn_sched_barrier(0);
}
__device__ __forceinline__ void wait_lgkm0() {
  asm volatile("s_waitcnt lgkmcnt(0)" ::: "memory");
  __builtin_amdgcn_sched_barrier(0);
}
// bijective XCD swizzle for 72 = 8 * 9
__device__ __forceinline__ int tswz(int x) { return (x & 7) * 9 + (x >> 3); }

#define MFMA(a,b,c) __builtin_amdgcn_mfma_f32_16x16x32_bf16((a),(b),(c),0,0,0)

// ---------------- merged fp32 [R][C] -> bf16 [C][R] transpose for all 3 weights ----
__global__ __launch_bounds__(256) void k_cvt_all(
    const float* __restrict__ gw, const float* __restrict__ uw,
    const float* __restrict__ dw,
    u16* __restrict__ gT, u16* __restrict__ uT, u16* __restrict__ dT) {
  int bx = blockIdx.x;
  int grp = bx >> 13;          // 0=g, 1=u, 2=d
  int idx = bx & 8191;
  int e = idx >> 10;
  int rem = idx & 1023;
  const float* in; u16* out; int R, C, cx, cy;
  if (grp == 0)      { in = gw; out = gT; R = D_HID; C = F_INT; cx = rem & 63; cy = rem >> 6; }
  else if (grp == 1) { in = uw; out = uT; R = D_HID; C = F_INT; cx = rem & 63; cy = rem >> 6; }
  else               { in = dw; out = dT; R = F_INT; C = D_HID; cx = rem & 15; cy = rem >> 4; }
  const size_t mat = (size_t)R * C;
  const float* ip = in + (size_t)e * mat;
  u16* op = out + (size_t)e * mat;
  int c0 = cx * 64, r0 = cy * 64;
  __shared__ float Tf[64][68];
  int t = threadIdx.x;
#pragma unroll
  for (int p = 0; p < 4; p++) {
    int r = p * 16 + (t >> 4);
    int c = (t & 15) * 4;
    float4 v = *(const float4*)(ip + (size_t)(r0 + r) * C + (c0 + c));
    *(float4*)&Tf[r][c] = v;
  }
  __syncthreads();
  int f = t >> 2, seg = (t & 3) * 16;
  union { u16 s[8]; uint4 q; } o0, o1;
#pragma unroll
  for (int j = 0; j < 8; j++) {
    o0.s[j] = f2bf(Tf[seg + j][f]);
    o1.s[j] = f2bf(Tf[seg + 8 + j][f]);
  }
  *(uint4*)(op + (size_t)(c0 + f) * R + r0 + seg) = o0.q;
  *(uint4*)(op + (size_t)(c0 + f) * R + r0 + seg + 8) = o1.q;
}

// ---------------- router: one wave per token, fp64 accumulation ----------------
__global__ __launch_bounds__(256) void k_router(const float* __restrict__ h,
                                                const float* __restrict__ rw,
                                                u16* __restrict__ hb,
                                                int* __restrict__ cntB,
                                                float* __restrict__ psumB,
                                                int* __restrict__ topk_e,
                                                float* __restrict__ topk_w) {
  int t = blockIdx.x * 4 + (threadIdx.x >> 6);
  int l = threadIdx.x & 63;
  const float* hr = h + (size_t)t * D_HID;
  u16* hbr = hb + (size_t)t * D_HID;
  double acc[NEXP];
#pragma unroll
  for (int e = 0; e < NEXP; e++) acc[e] = 0.0;
#pragma unroll
  for (int it = 0; it < 4; it++) {
    int i = it * 256 + l * 4;
    float4 x4 = *(const float4*)(hr + i);
    union { u16 s[4]; uint2 q; } o;
    o.s[0] = f2bf(x4.x); o.s[1] = f2bf(x4.y); o.s[2] = f2bf(x4.z); o.s[3] = f2bf(x4.w);
    *(uint2*)(hbr + i) = o.q;
    const float* xp = &x4.x;
#pragma unroll
    for (int k = 0; k < 4; k++) {
      double x = (double)xp[k];
      const float4* r4 = (const float4*)(rw + (size_t)(i + k) * NEXP);
      float4 a = r4[0], b = r4[1];
      acc[0] += x * a.x; acc[1] += x * a.y; acc[2] += x * a.z; acc[3] += x * a.w;
      acc[4] += x * b.x; acc[5] += x * b.y; acc[6] += x * b.z; acc[7] += x * b.w;
    }
  }
#pragma unroll
  for (int m = 32; m >= 1; m >>= 1) {
#pragma unroll
    for (int e = 0; e < NEXP; e++) acc[e] += __shfl_xor(acc[e], m, 64);
  }
  if (l == 0) {
    double mx = acc[0];
#pragma unroll
    for (int e = 1; e < NEXP; e++) mx = fmax(mx, acc[e]);
    double p[NEXP], s = 0.0;
#pragma unroll
    for (int e = 0; e < NEXP; e++) { p[e] = exp(acc[e] - mx); s += p[e]; }
    int i0 = 0;
#pragma unroll
    for (int e = 1; e < NEXP; e++) if (p[e] > p[i0]) i0 = e;
    int i1 = (i0 == 0) ? 1 : 0;
#pragma unroll
    for (int e = 0; e < NEXP; e++) if (e != i0 && p[e] > p[i1]) i1 = e;
    double w0 = p[i0] / (p[i0] + p[i1]);
    topk_e[t] = i0 | (i1 << 8);
    topk_w[2 * t] = (float)w0;
    topk_w[2 * t + 1] = (float)(1.0 - w0);
    int bank = t & (CBANKS - 1);
    atomicAdd(&cntB[i0 * CBANKS + bank], 1);
    atomicAdd(&cntB[i1 * CBANKS + bank], 1);
    float inv = (float)(1.0 / s);
#pragma unroll
    for (int e = 0; e < NEXP; e++) atomicAdd(&psumB[e * CBANKS + bank], (float)p[e] * inv);
  }
}

// ---------------- scan: wave-parallel reduce, offsets, tile table, loss ----------------
__global__ void k_scan(const int* __restrict__ cntB, const float* __restrict__ psumB,
                       int* __restrict__ offs, int4* __restrict__ tiles,
                       int* __restrict__ meta, float* __restrict__ loss_out,
                       int* __restrict__ cnt2) {
  int l = threadIdx.x;   // 64 threads, one wave
  int cs[NEXP]; float ps[NEXP];
#pragma unroll
  for (int e = 0; e < NEXP; e++) {
    int c = cntB[e * CBANKS + l];
    float p = psumB[e * CBANKS + l];
#pragma unroll
    for (int m = 32; m >= 1; m >>= 1) {
      c += __shfl_xor(c, m, 64);
      p += __shfl_xor(p, m, 64);
    }
    cs[e] = c; ps[e] = p;
  }
  if (l == 0) {
    int off = 0, tc = 0;
    double loss = 0.0;
    for (int e = 0; e < NEXP; e++) {
      loss += ((double)cs[e] / (double)T_TOK) * ((double)ps[e] / (double)T_TOK);
      offs[e] = off;
      int nt = (cs[e] + BMR - 1) / BMR;
      for (int j = 0; j < nt; j++) {
        int rem = cs[e] - j * BMR;
        tiles[tc] = make_int4(e, off + j * BMR, rem < BMR ? rem : BMR, 0);
        tc++;
      }
      off += cs[e];
      cnt2[e] = 0;
    }
    offs[NEXP] = off;
    meta[0] = tc;
    loss_out[0] = (float)(loss * (double)NEXP);
  }
}

// ---------------- scatter tokens into expert-grouped order (+ inverse map) ----------------
__global__ __launch_bounds__(256) void k_scatter(const int* __restrict__ topk_e,
                                                 const float* __restrict__ topk_w,
                                                 const int* __restrict__ offs,
                                                 int* __restrict__ cnt2,
                                                 int* __restrict__ rowtok,
                                                 float* __restrict__ roww,
                                                 int* __restrict__ invmap) {
  int t = blockIdx.x * 256 + threadIdx.x;
  if (t >= T_TOK) return;
  int ee = topk_e[t];
#pragma unroll
  for (int k = 0; k < 2; k++) {
    int e = (ee >> (8 * k)) & 255;
    int pos = offs[e] + atomicAdd(&cnt2[e], 1);
    rowtok[pos] = t;
    roww[pos] = topk_w[2 * t + k];
    invmap[2 * t + k] = pos;
  }
}

// ---------------- combine: out[t] = sum over 2 slots x 4 K-quarters of P ----------------
// P layout: P01 holds z=0 (rows 0..NT2) and z=1 (rows NT2..2*NT2); P23 holds z=2,3.
template <int PB>
__global__ __launch_bounds__(256) void k_combine(const void* __restrict__ P01,
                                                 const void* __restrict__ P23,
                                                 const int* __restrict__ invmap,
                                                 float* __restrict__ out) {
  int t = blockIdx.x;
  int d = threadIdx.x * 4;
  int pA = invmap[2 * t], pB = invmap[2 * t + 1];
  float4 s; s.x = s.y = s.z = s.w = 0.f;
#pragma unroll
  for (int h = 0; h < 2; h++) {
    const void* bp = h ? P23 : P01;
#pragma unroll
    for (int z = 0; z < 2; z++) {
#pragma unroll
      for (int sl = 0; sl < 2; sl++) {
        size_t row = (size_t)z * NT2 + (sl ? pB : pA);
        size_t idx = row * D_HID + d;
        if constexpr (PB) {
          uint2 q = *(const uint2*)((const u16*)bp + idx);
          s.x += __uint_as_float((q.x & 0xFFFFu) << 16);
          s.y += __uint_as_float(q.x & 0xFFFF0000u);
          s.z += __uint_as_float((q.y & 0xFFFFu) << 16);
          s.w += __uint_as_float(q.y & 0xFFFF0000u);
        } else {
          float4 v = *(const float4*)((const float*)bp + idx);
          s.x += v.x; s.y += v.y; s.z += v.z; s.w += v.w;
        }
      }
    }
  }
  *(float4*)(out + (size_t)t * D_HID + d) = s;
}

// ---------------- 256-row 8-phase grouped GEMM (R3 TILE structure) ----------------
// MODE 0: fused gate+up -> G = silu(g)*u.
// MODE 2: down -> atomicAdd(out, C*roww)   [fallback, chunked path]
// MODE 3: down -> plain store P[kz][row][d] = C*roww (P fp32 if PB=0, bf16 if PB=1;
//         kz<2 -> outP1 base, kz>=2 -> outP2 base)
template <int MODE, int PB>
__global__ __launch_bounds__(512, 2) void k_mm8(
    const u16* __restrict__ Asrc, const u16* __restrict__ Bsrc,
    const u16* __restrict__ Bsrc2,
    const int4* __restrict__ tiles, const int* __restrict__ meta,
    const int* __restrict__ rowtok, const float* __restrict__ roww,
    u16* __restrict__ G, float* __restrict__ out, void* __restrict__ outP2,
    int fcb, int FC, int KLEN) {
  int bx = tswz(blockIdx.x);
  if (bx >= meta[0]) return;
  int4 td = tiles[bx];
  int eid = td.x, row0 = td.y, nrows = td.z;
  int by = blockIdx.y;
  int kz = blockIdx.z;
  size_t kz_byte = (size_t)kz * KLEN * 2;

  __shared__ __align__(16) u16 lds[2][2][BMR][64];   // [buf][A=0/B=1][row][k]

  int tid = threadIdx.x;
  int l = tid & 63, wid = tid >> 6;
  int wr = wid >> 2, wc = wid & 3;

  // ---- staging source pointers (4 calls per matrix, 64 rows each) ----
  int rr0 = wid * 8 + (l >> 3);                  // row within 64-row group
  int sw = ((l & 7) ^ (rr0 & 7)) << 4;           // XOR-swizzled 16B chunk
  const char* pA[4]; const char* pB[4];
#pragma unroll
  for (int j = 0; j < 4; j++) {
    int rr = j * 64 + rr0;
    if constexpr (MODE == 0) {
      int tok = rowtok[row0 + ((rr < nrows) ? rr : 0)];
      pA[j] = (const char*)Asrc + (size_t)tok * (D_HID * 2) + sw;
      const u16* wsrc = (j < 2) ? Bsrc : Bsrc2;     // gate rows 0-127, up rows 128-255
      int frow = fcb + by * 128 + (rr & 127);
      pB[j] = (const char*)wsrc + ((size_t)eid * F_INT + frow) * (D_HID * 2) + sw;
    } else {
      pA[j] = (const char*)Asrc + (size_t)(row0 + rr) * (FC * 2) + kz_byte + sw;
      int brow = by * 256 + rr;
      pB[j] = (const char*)Bsrc + ((size_t)eid * D_HID + brow) * (F_INT * 2) + kz_byte + sw;
    }
  }

  // ---- fragment-read offsets (de-swizzle; row&7 == l&7 for both A and B) ----
  int ch0 = (((l >> 4) + 0) ^ (l & 7)) << 4;
  int ch1 = (((l >> 4) + 4) ^ (l & 7)) << 4;
  int offA = (wr * 128 + (l & 15)) * 128;
  int offBn[4];
#pragma unroll
  for (int n = 0; n < 4; n++) {
    int r;
    if constexpr (MODE == 0)
      r = (n < 2) ? (wc * 32 + n * 16) : (128 + wc * 32 + (n - 2) * 16);
    else
      r = wc * 64 + n * 16;
    offBn[n] = 32768 + (r + (l & 15)) * 128;
  }
  const char* base = (const char*)&lds[0][0][0][0];
#define LDA(b,m,s) (*(const bf16x8*)(base + (b)*65536 + offA + (m)*2048 + ((s)?ch1:ch0)))
#define LDB(b,n,s) (*(const bf16x8*)(base + (b)*65536 + offBn[n] + ((s)?ch1:ch0)))

  f32x4 acc[8][4];
#pragma unroll
  for (int m = 0; m < 8; m++)
#pragma unroll
    for (int n = 0; n < 4; n++) acc[m][n] = f32x4{0.f, 0.f, 0.f, 0.f};

  auto STAGE = [&](int b, int mat, const char* const* p, int kt) {
#pragma unroll
    for (int j = 0; j < 4; j++)
      gload_lds16(p[j] + (size_t)kt * 128, &lds[b][mat][j * 64 + wid * 8][0]);
  };

  auto TILE = [&](int b, int kts, bool dostage, int vm) {
    bf16x8 fa[4][2], fb[4][2];
    // ---- ph1 ---- (12 ds_reads -> template's optional lgkmcnt(8) pre-drain)
#pragma unroll
    for (int m = 0; m < 4; m++) { fa[m][0] = LDA(b, m, 0); fa[m][1] = LDA(b, m, 1); }
#pragma unroll
    for (int n = 0; n < 2; n++) { fb[n][0] = LDB(b, n, 0); fb[n][1] = LDB(b, n, 1); }
    asm volatile("s_waitcnt lgkmcnt(8)" ::: "memory");
    __builtin_amdgcn_s_barrier();
    wait_lgkm0();
    __builtin_amdgcn_s_setprio(1);
#pragma unroll
    for (int m = 0; m < 4; m++)
#pragma unroll
      for (int n = 0; n < 2; n++) {
        acc[m][n] = MFMA(fa[m][0], fb[n][0], acc[m][n]);
        acc[m][n] = MFMA(fa[m][1], fb[n][1], acc[m][n]);
      }
    __builtin_amdgcn_s_setprio(0);
    __builtin_amdgcn_s_barrier();
    // ---- ph2 ----
#pragma unroll
    for (int n = 2; n < 4; n++) { fb[n][0] = LDB(b, n, 0); fb[n][1] = LDB(b, n, 1); }
    __builtin_amdgcn_s_barrier();
    wait_lgkm0();
    __builtin_amdgcn_s_setprio(1);
#pragma unroll
    for (int m = 0; m < 4; m++)
#pragma unroll
      for (int n = 2; n < 4; n++) {
        acc[m][n] = MFMA(fa[m][0], fb[n][0], acc[m][n]);
        acc[m][n] = MFMA(fa[m][1], fb[n][1], acc[m][n]);
      }
    __builtin_amdgcn_s_setprio(0);
    __builtin_amdgcn_s_barrier();
    // ---- ph3 ---- (B halves of buf b free after ph2 barrier)
#pragma unroll
    for (int m = 0; m < 4; m++) { fa[m][0] = LDA(b, 4 + m, 0); fa[m][1] = LDA(b, 4 + m, 1); }
    if (dostage) STAGE(b, 1, pB, kts);
    __builtin_amdgcn_s_barrier();
    wait_lgkm0();
    __builtin_amdgcn_s_setprio(1);
#pragma unroll
    for (int m = 0; m < 4; m++)
#pragma unroll
      for (int n = 0; n < 2; n++) {
        acc[4 + m][n] = MFMA(fa[m][0], fb[n][0], acc[4 + m][n]);
        acc[4 + m][n] = MFMA(fa[m][1], fb[n][1], acc[4 + m][n]);
      }
    __builtin_amdgcn_s_setprio(0);
    __builtin_amdgcn_s_barrier();
    // ---- ph4 ---- (A halves of buf b free after ph3 barrier)
    if (dostage) STAGE(b, 0, pA, kts);
    if (vm == 8) wait_vm8();
    else if (vm == 0) wait_vm0();
    __builtin_amdgcn_s_barrier();
    __builtin_amdgcn_s_setprio(1);
#pragma unroll
    for (int m = 0; m < 4; m++)
#pragma unroll
      for (int n = 2; n < 4; n++) {
        acc[4 + m][n] = MFMA(fa[m][0], fb[n][0], acc[4 + m][n]);
        acc[4 + m][n] = MFMA(fa[m][1], fb[n][1], acc[4 + m][n]);
      }
    __builtin_amdgcn_s_setprio(0);
    __builtin_amdgcn_s_barrier();
  };

  // ---- prologue: stage tiles 0 (buf0) and 1 (buf1) ----
  int NT = KLEN / 64;
  STAGE(0, 1, pB, 0); STAGE(0, 0, pA, 0);
  STAGE(1, 1, pB, 1); STAGE(1, 0, pA, 1);
  wait_vm8();
  __builtin_amdgcn_s_barrier();

  int NIT = NT / 2;
  for (int it = 0; it < NIT - 1; ++it) {
    TILE(0, 2 * it + 2, true, 8);
    TILE(1, 2 * it + 3, true, 8);
  }
  TILE(0, 0, false, 0);
  TILE(1, 0, false, -1);

  // ---- epilogue ----
  int lr = (l >> 4) * 4, lc = l & 15;
#pragma unroll
  for (int m = 0; m < 8; m++) {
    int rbase = wr * 128 + m * 16 + lr;
#pragma unroll
    for (int j = 0; j < 4; j++) {
      int r = rbase + j;
      if (r < nrows) {
        if constexpr (MODE == 0) {
          size_t gb = (size_t)(row0 + r) * FC + by * 128 + wc * 32 + lc;
#pragma unroll
          for (int n = 0; n < 2; n++) {
            float g = acc[m][n][j], u = acc[m][n + 2][j];
            float sv = g / (1.0f + __expf(-g));
            G[gb + n * 16] = f2bf(sv * u);
          }
        } else if constexpr (MODE == 2) {
          float w = roww[row0 + r];
          int tok = rowtok[row0 + r];
          size_t ob = (size_t)tok * D_HID + by * 256 + wc * 64 + lc;
#pragma unroll
          for (int n = 0; n < 4; n++) atomicAdd(&out[ob + n * 16], acc[m][n][j] * w);
        } else {  // MODE 3
          float w = roww[row0 + r];
          size_t pb = ((size_t)(kz & 1) * NT2 + (row0 + r)) * D_HID + by * 256 + wc * 64 + lc;
          if constexpr (PB) {
            u16* dst = (u16*)(kz < 2 ? (void*)out : outP2);
#pragma unroll
            for (int n = 0; n < 4; n++) dst[pb + n * 16] = f2bf(acc[m][n][j] * w);
          } else {
            float* dst = (float*)(kz < 2 ? (void*)out : outP2);
#pragma unroll
            for (int n = 0; n < 4; n++) dst[pb + n * 16] = acc[m][n][j] * w;
          }
        }
      }
    }
  }
#undef LDA
#undef LDB
}

extern "C" void kernel_launch(void* const* d_in, const int* in_sizes, int n_in,
                              void* d_out, int out_size, void* d_ws, size_t ws_size,
                              hipStream_t stream) {
  (void)in_sizes; (void)n_in;
  const float* h  = (const float*)d_in[0];
  const float* rw = (const float*)d_in[1];
  const float* gw = (const float*)d_in[2];
  const float* uw = (const float*)d_in[3];
  const float* dw = (const float*)d_in[4];
  float* out = (float*)d_out;

  char* base = (char*)d_ws;
  size_t off = 0;
  auto alloc = [&](size_t b) -> char* {
    char* r = base + off;
    off += (b + 255) & ~(size_t)255;
    return r;
  };

  u16*   hb     = (u16*)alloc((size_t)T_TOK * D_HID * 2);
  int*   cntB   = (int*)alloc(NEXP * CBANKS * 4);
  float* psumB  = (float*)alloc(NEXP * CBANKS * 4);
  int*   offs   = (int*)alloc((NEXP + 1) * 4);
  int*   cnt2   = (int*)alloc(NEXP * 4);
  int*   meta   = (int*)alloc(64);
  int4*  tiles  = (int4*)alloc(NTIL * sizeof(int4));
  int*   topk_e = (int*)alloc(T_TOK * 4);
  float* topk_w = (float*)alloc((size_t)T_TOK * 2 * 4);
  int*   rowtok = (int*)alloc(NT2 * 4);
  float* roww   = (float*)alloc(NT2 * 4);
  int*   invmap = (int*)alloc(NT2 * 4);

  size_t zbytes = (size_t)((char*)topk_e - (char*)cntB);

  const size_t GROWS = NT2 + (size_t)BMR * NEXP;   // 18432 padded rows
  const size_t EDF = (size_t)NEXP * D_HID * F_INT;
  size_t avail = (ws_size > off) ? ws_size - off : 0;
  auto need = [&](int nc) -> size_t {
    return 3 * EDF * 2 + GROWS * (size_t)(F_INT / nc) * 2 + 65536;
  };
  int nchunk = 4;
  if      (avail >= need(1)) nchunk = 1;
  else if (avail >= need(2)) nchunk = 2;
  u16* gT = (u16*)alloc(EDF * 2);
  u16* uT = (u16*)alloc(EDF * 2);
  u16* dT = (u16*)alloc(EDF * 2);
  int FC = F_INT / nchunk;
  u16* G = (u16*)alloc(GROWS * (size_t)FC * 2);

  hipMemsetAsync(cntB, 0, zbytes, stream);
  if (nchunk != 1) hipMemsetAsync(d_out, 0, (size_t)out_size * 4, stream);

  k_router<<<T_TOK / 4, 256, 0, stream>>>(h, rw, hb, cntB, psumB, topk_e, topk_w);
  k_scan<<<1, 64, 0, stream>>>(cntB, psumB, offs, tiles, meta, out + (out_size - 1), cnt2);
  k_scatter<<<T_TOK / 256, 256, 0, stream>>>(topk_e, topk_w, offs, cnt2, rowtok, roww, invmap);
  k_cvt_all<<<24576, 256, 0, stream>>>(gw, uw, dw, gT, uT, dT);

  if (nchunk == 1) {
    // Down with 4-way K-split. P slices z=0,1 alias gT+uT (dead after gateup,
    // exactly 2*NT2*D_HID*4 = 134217728 B). Slices z=2,3: fresh fp32 alloc if
    // workspace allows (exact), else bf16 packed into the same alias region.
    const size_t pfresh = (size_t)2 * NT2 * D_HID * 4;
    bool fp32p = (avail >= need(1) + pfresh + 256);
    dim3 g1(NTIL, F_INT / 128, 1);
    dim3 g2(NTIL, D_HID / 256, 4);
    k_mm8<0, 0><<<g1, 512, 0, stream>>>(hb, gT, uT, tiles, meta, rowtok, roww,
                                        G, out, nullptr, 0, F_INT, D_HID);
    if (fp32p) {
      float* P01 = (float*)gT;
      float* P23 = (float*)alloc(pfresh);
      k_mm8<3, 0><<<g2, 512, 0, stream>>>(G, dT, dT, tiles, meta, rowtok, roww,
                                          G, P01, (void*)P23, 0, F_INT, F_INT / 4);
      k_combine<0><<<T_TOK, 256, 0, stream>>>(P01, P23, invmap, out);
    } else {
      u16* P01 = (u16*)gT;                                   // bf16: 4 slices fit 134 MB
      u16* P23 = (u16*)gT + (size_t)2 * NT2 * D_HID;
      k_mm8<3, 1><<<g2, 512, 0, stream>>>(G, dT, dT, tiles, meta, rowtok, roww,
                                          G, (float*)P01, (void*)P23, 0, F_INT, F_INT / 4);
      k_combine<1><<<T_TOK, 256, 0, stream>>>(P01, P23, invmap, out);
    }
  } else {
    for (int c = 0; c < nchunk; c++) {
      int fcb = c * FC;
      dim3 g1(NTIL, FC / 128, 1);
      dim3 g2(NTIL, D_HID / 256, 2);
      k_mm8<0, 0><<<g1, 512, 0, stream>>>(hb, gT, uT, tiles, meta, rowtok, roww,
                                          G, out, nullptr, fcb, FC, D_HID);
      k_mm8<2, 0><<<g2, 512, 0, stream>>>(G, dT, dT, tiles, meta, rowtok, roww,
                                          G, out, nullptr, fcb, FC, FC / 2);
    }
  }
}

// Round 10
// 802.191 us; speedup vs baseline: 1.0489x; 1.0489x over previous
//
#include <hip/hip_runtime.h>
#include <stdint.h>

#define T_TOK 8192
#define D_HID 1024
#define F_INT 4096
#define NEXP 8
#define NT2 (T_TOK*2)
#define BMR 256
#define NTIL 72              // max 256-row tiles: 16384/256 + 8
#define CBANKS 64

typedef __attribute__((ext_vector_type(4))) float f32x4;
typedef __attribute__((ext_vector_type(8))) __bf16 bf16x8;
typedef unsigned short u16;

__device__ __forceinline__ unsigned short f2bf(float x) {
  unsigned int u = __float_as_uint(x);
  u = u + 0x7FFFu + ((u >> 16) & 1u);
  return (unsigned short)(u >> 16);
}
__device__ __forceinline__ void gload_lds16(const void* g, void* l) {
  __builtin_amdgcn_global_load_lds(
      (const __attribute__((address_space(1))) unsigned int*)g,
      (__attribute__((address_space(3))) unsigned int*)l, 16, 0, 0);
}
__device__ __forceinline__ void wait_vm8() {
  asm volatile("s_waitcnt vmcnt(8)" ::: "memory");
  __builtin_amdgcn_sched_barrier(0);
}
__device__ __forceinline__ void wait_vm0() {
  asm volatile("s_waitcnt vmcnt(0)" ::: "memory");
  __builtin_amdgcn_sched_barrier(0);
}
__device__ __forceinline__ void wait_lgkm0() {
  asm volatile("s_waitcnt lgkmcnt(0)" ::: "memory");
  __builtin_amdgcn_sched_barrier(0);
}
// bijective XCD swizzle for 72 = 8 * 9
__device__ __forceinline__ int tswz(int x) { return (x & 7) * 9 + (x >> 3); }

#define MFMA(a,b,c) __builtin_amdgcn_mfma_f32_16x16x32_bf16((a),(b),(c),0,0,0)

// ---------------- merged fp32 [R][C] -> bf16 [C][R] transpose for all 3 weights ----
__global__ __launch_bounds__(256) void k_cvt_all(
    const float* __restrict__ gw, const float* __restrict__ uw,
    const float* __restrict__ dw,
    u16* __restrict__ gT, u16* __restrict__ uT, u16* __restrict__ dT) {
  int bx = blockIdx.x;
  int grp = bx >> 13;          // 0=g, 1=u, 2=d
  int idx = bx & 8191;
  int e = idx >> 10;
  int rem = idx & 1023;
  const float* in; u16* out; int R, C, cx, cy;
  if (grp == 0)      { in = gw; out = gT; R = D_HID; C = F_INT; cx = rem & 63; cy = rem >> 6; }
  else if (grp == 1) { in = uw; out = uT; R = D_HID; C = F_INT; cx = rem & 63; cy = rem >> 6; }
  else               { in = dw; out = dT; R = F_INT; C = D_HID; cx = rem & 15; cy = rem >> 4; }
  const size_t mat = (size_t)R * C;
  const float* ip = in + (size_t)e * mat;
  u16* op = out + (size_t)e * mat;
  int c0 = cx * 64, r0 = cy * 64;
  __shared__ float Tf[64][68];
  int t = threadIdx.x;
#pragma unroll
  for (int p = 0; p < 4; p++) {
    int r = p * 16 + (t >> 4);
    int c = (t & 15) * 4;
    float4 v = *(const float4*)(ip + (size_t)(r0 + r) * C + (c0 + c));
    *(float4*)&Tf[r][c] = v;
  }
  __syncthreads();
  int f = t >> 2, seg = (t & 3) * 16;
  union { u16 s[8]; uint4 q; } o0, o1;
#pragma unroll
  for (int j = 0; j < 8; j++) {
    o0.s[j] = f2bf(Tf[seg + j][f]);
    o1.s[j] = f2bf(Tf[seg + 8 + j][f]);
  }
  *(uint4*)(op + (size_t)(c0 + f) * R + r0 + seg) = o0.q;
  *(uint4*)(op + (size_t)(c0 + f) * R + r0 + seg + 8) = o1.q;
}

// ---------------- router: one wave per token, fp64 accumulation ----------------
__global__ __launch_bounds__(256) void k_router(const float* __restrict__ h,
                                                const float* __restrict__ rw,
                                                u16* __restrict__ hb,
                                                int* __restrict__ cntB,
                                                float* __restrict__ psumB,
                                                int* __restrict__ topk_e,
                                                float* __restrict__ topk_w) {
  int t = blockIdx.x * 4 + (threadIdx.x >> 6);
  int l = threadIdx.x & 63;
  const float* hr = h + (size_t)t * D_HID;
  u16* hbr = hb + (size_t)t * D_HID;
  double acc[NEXP];
#pragma unroll
  for (int e = 0; e < NEXP; e++) acc[e] = 0.0;
#pragma unroll
  for (int it = 0; it < 4; it++) {
    int i = it * 256 + l * 4;
    float4 x4 = *(const float4*)(hr + i);
    union { u16 s[4]; uint2 q; } o;
    o.s[0] = f2bf(x4.x); o.s[1] = f2bf(x4.y); o.s[2] = f2bf(x4.z); o.s[3] = f2bf(x4.w);
    *(uint2*)(hbr + i) = o.q;
    const float* xp = &x4.x;
#pragma unroll
    for (int k = 0; k < 4; k++) {
      double x = (double)xp[k];
      const float4* r4 = (const float4*)(rw + (size_t)(i + k) * NEXP);
      float4 a = r4[0], b = r4[1];
      acc[0] += x * a.x; acc[1] += x * a.y; acc[2] += x * a.z; acc[3] += x * a.w;
      acc[4] += x * b.x; acc[5] += x * b.y; acc[6] += x * b.z; acc[7] += x * b.w;
    }
  }
#pragma unroll
  for (int m = 32; m >= 1; m >>= 1) {
#pragma unroll
    for (int e = 0; e < NEXP; e++) acc[e] += __shfl_xor(acc[e], m, 64);
  }
  if (l == 0) {
    double mx = acc[0];
#pragma unroll
    for (int e = 1; e < NEXP; e++) mx = fmax(mx, acc[e]);
    double p[NEXP], s = 0.0;
#pragma unroll
    for (int e = 0; e < NEXP; e++) { p[e] = exp(acc[e] - mx); s += p[e]; }
    int i0 = 0;
#pragma unroll
    for (int e = 1; e < NEXP; e++) if (p[e] > p[i0]) i0 = e;
    int i1 = (i0 == 0) ? 1 : 0;
#pragma unroll
    for (int e = 0; e < NEXP; e++) if (e != i0 && p[e] > p[i1]) i1 = e;
    double w0 = p[i0] / (p[i0] + p[i1]);
    topk_e[t] = i0 | (i1 << 8);
    topk_w[2 * t] = (float)w0;
    topk_w[2 * t + 1] = (float)(1.0 - w0);
    int bank = t & (CBANKS - 1);
    atomicAdd(&cntB[i0 * CBANKS + bank], 1);
    atomicAdd(&cntB[i1 * CBANKS + bank], 1);
    float inv = (float)(1.0 / s);
#pragma unroll
    for (int e = 0; e < NEXP; e++) atomicAdd(&psumB[e * CBANKS + bank], (float)p[e] * inv);
  }
}

// ---------------- scan: wave-parallel reduce, offsets, tile table, loss ----------------
__global__ void k_scan(const int* __restrict__ cntB, const float* __restrict__ psumB,
                       int* __restrict__ offs, int4* __restrict__ tiles,
                       int* __restrict__ meta, float* __restrict__ loss_out,
                       int* __restrict__ cnt2) {
  int l = threadIdx.x;   // 64 threads, one wave
  int cs[NEXP]; float ps[NEXP];
#pragma unroll
  for (int e = 0; e < NEXP; e++) {
    int c = cntB[e * CBANKS + l];
    float p = psumB[e * CBANKS + l];
#pragma unroll
    for (int m = 32; m >= 1; m >>= 1) {
      c += __shfl_xor(c, m, 64);
      p += __shfl_xor(p, m, 64);
    }
    cs[e] = c; ps[e] = p;
  }
  if (l == 0) {
    int off = 0, tc = 0;
    double loss = 0.0;
    for (int e = 0; e < NEXP; e++) {
      loss += ((double)cs[e] / (double)T_TOK) * ((double)ps[e] / (double)T_TOK);
      offs[e] = off;
      int nt = (cs[e] + BMR - 1) / BMR;
      for (int j = 0; j < nt; j++) {
        int rem = cs[e] - j * BMR;
        tiles[tc] = make_int4(e, off + j * BMR, rem < BMR ? rem : BMR, 0);
        tc++;
      }
      off += cs[e];
      cnt2[e] = 0;
    }
    offs[NEXP] = off;
    meta[0] = tc;
    loss_out[0] = (float)(loss * (double)NEXP);
  }
}

// ---------------- scatter tokens into expert-grouped order (+ inverse map) ----------------
__global__ __launch_bounds__(256) void k_scatter(const int* __restrict__ topk_e,
                                                 const float* __restrict__ topk_w,
                                                 const int* __restrict__ offs,
                                                 int* __restrict__ cnt2,
                                                 int* __restrict__ rowtok,
                                                 float* __restrict__ roww,
                                                 int* __restrict__ invmap) {
  int t = blockIdx.x * 256 + threadIdx.x;
  if (t >= T_TOK) return;
  int ee = topk_e[t];
#pragma unroll
  for (int k = 0; k < 2; k++) {
    int e = (ee >> (8 * k)) & 255;
    int pos = offs[e] + atomicAdd(&cnt2[e], 1);
    rowtok[pos] = t;
    roww[pos] = topk_w[2 * t + k];
    invmap[2 * t + k] = pos;
  }
}

// ---------------- combine: out[t] = sum over 2 slots x 2 K-halves of P ----------------
__global__ __launch_bounds__(256) void k_combine(const float* __restrict__ P,
                                                 const int* __restrict__ invmap,
                                                 float* __restrict__ out) {
  int t = blockIdx.x;
  int d = threadIdx.x * 4;
  int pA = invmap[2 * t], pB = invmap[2 * t + 1];
  float4 a0 = *(const float4*)(P + (size_t)pA * D_HID + d);
  float4 a1 = *(const float4*)(P + ((size_t)NT2 + pA) * D_HID + d);
  float4 b0 = *(const float4*)(P + (size_t)pB * D_HID + d);
  float4 b1 = *(const float4*)(P + ((size_t)NT2 + pB) * D_HID + d);
  float4 r;
  r.x = (a0.x + a1.x) + (b0.x + b1.x);
  r.y = (a0.y + a1.y) + (b0.y + b1.y);
  r.z = (a0.z + a1.z) + (b0.z + b1.z);
  r.w = (a0.w + a1.w) + (b0.w + b1.w);
  *(float4*)(out + (size_t)t * D_HID + d) = r;
}

// ---------------- 256-row 8-phase grouped GEMM (R3 TILE structure) ----------------
// MODE 0: fused gate+up -> G = silu(g)*u.
// MODE 2: down -> atomicAdd(out, C*roww)   [fallback, chunked path]
// MODE 3: down -> plain store P[kz][row][d] = C*roww  [combine path]
//         grid.x = NTIL*4 packing (tile,by); per-XCD chunk = 9 tiles x 4 by so
//         blocks sharing a G-panel (same tile, 4 by) land on ONE XCD's L2.
template <int MODE>
__global__ __launch_bounds__(512, 2) void k_mm8(
    const u16* __restrict__ Asrc, const u16* __restrict__ Bsrc,
    const u16* __restrict__ Bsrc2,
    const int4* __restrict__ tiles, const int* __restrict__ meta,
    const int* __restrict__ rowtok, const float* __restrict__ roww,
    u16* __restrict__ G, float* __restrict__ out,
    int fcb, int FC, int KLEN) {
  int bx, by;
  if constexpr (MODE == 3) {
    int s = ((int)blockIdx.x & 7) * 36 + ((int)blockIdx.x >> 3);  // 288 = 8*36 bijective
    bx = s >> 2; by = s & 3;
  } else {
    bx = tswz(blockIdx.x); by = blockIdx.y;
  }
  if (bx >= meta[0]) return;
  int4 td = tiles[bx];
  int eid = td.x, row0 = td.y, nrows = td.z;
  int kz = blockIdx.z;
  size_t kz_byte = (size_t)kz * KLEN * 2;

  __shared__ __align__(16) u16 lds[2][2][BMR][64];   // [buf][A=0/B=1][row][k]

  int tid = threadIdx.x;
  int l = tid & 63, wid = tid >> 6;
  int wr = wid >> 2, wc = wid & 3;

  // ---- staging source pointers (4 calls per matrix, 64 rows each) ----
  int rr0 = wid * 8 + (l >> 3);                  // row within 64-row group
  int sw = ((l & 7) ^ (rr0 & 7)) << 4;           // XOR-swizzled 16B chunk
  const char* pA[4]; const char* pB[4];
#pragma unroll
  for (int j = 0; j < 4; j++) {
    int rr = j * 64 + rr0;
    if constexpr (MODE == 0) {
      int tok = rowtok[row0 + ((rr < nrows) ? rr : 0)];
      pA[j] = (const char*)Asrc + (size_t)tok * (D_HID * 2) + sw;
      const u16* wsrc = (j < 2) ? Bsrc : Bsrc2;     // gate rows 0-127, up rows 128-255
      int frow = fcb + by * 128 + (rr & 127);
      pB[j] = (const char*)wsrc + ((size_t)eid * F_INT + frow) * (D_HID * 2) + sw;
    } else {
      pA[j] = (const char*)Asrc + (size_t)(row0 + rr) * (FC * 2) + kz_byte + sw;
      int brow = by * 256 + rr;
      pB[j] = (const char*)Bsrc + ((size_t)eid * D_HID + brow) * (F_INT * 2) + kz_byte + sw;
    }
  }

  // ---- fragment-read offsets (de-swizzle; row&7 == l&7 for both A and B) ----
  int ch0 = (((l >> 4) + 0) ^ (l & 7)) << 4;
  int ch1 = (((l >> 4) + 4) ^ (l & 7)) << 4;
  int offA = (wr * 128 + (l & 15)) * 128;
  int offBn[4];
#pragma unroll
  for (int n = 0; n < 4; n++) {
    int r;
    if constexpr (MODE == 0)
      r = (n < 2) ? (wc * 32 + n * 16) : (128 + wc * 32 + (n - 2) * 16);
    else
      r = wc * 64 + n * 16;
    offBn[n] = 32768 + (r + (l & 15)) * 128;
  }
  const char* base = (const char*)&lds[0][0][0][0];
#define LDA(b,m,s) (*(const bf16x8*)(base + (b)*65536 + offA + (m)*2048 + ((s)?ch1:ch0)))
#define LDB(b,n,s) (*(const bf16x8*)(base + (b)*65536 + offBn[n] + ((s)?ch1:ch0)))

  f32x4 acc[8][4];
#pragma unroll
  for (int m = 0; m < 8; m++)
#pragma unroll
    for (int n = 0; n < 4; n++) acc[m][n] = f32x4{0.f, 0.f, 0.f, 0.f};

  auto STAGE = [&](int b, int mat, const char* const* p, int kt) {
#pragma unroll
    for (int j = 0; j < 4; j++)
      gload_lds16(p[j] + (size_t)kt * 128, &lds[b][mat][j * 64 + wid * 8][0]);
  };

  auto TILE = [&](int b, int kts, bool dostage, int vm) {
    bf16x8 fa[4][2], fb[4][2];
    // ---- ph1 ---- (12 ds_reads -> template's optional lgkmcnt(8) pre-drain)
#pragma unroll
    for (int m = 0; m < 4; m++) { fa[m][0] = LDA(b, m, 0); fa[m][1] = LDA(b, m, 1); }
#pragma unroll
    for (int n = 0; n < 2; n++) { fb[n][0] = LDB(b, n, 0); fb[n][1] = LDB(b, n, 1); }
    asm volatile("s_waitcnt lgkmcnt(8)" ::: "memory");
    __builtin_amdgcn_s_barrier();
    wait_lgkm0();
    __builtin_amdgcn_s_setprio(1);
#pragma unroll
    for (int m = 0; m < 4; m++)
#pragma unroll
      for (int n = 0; n < 2; n++) {
        acc[m][n] = MFMA(fa[m][0], fb[n][0], acc[m][n]);
        acc[m][n] = MFMA(fa[m][1], fb[n][1], acc[m][n]);
      }
    __builtin_amdgcn_s_setprio(0);
    __builtin_amdgcn_s_barrier();
    // ---- ph2 ----
#pragma unroll
    for (int n = 2; n < 4; n++) { fb[n][0] = LDB(b, n, 0); fb[n][1] = LDB(b, n, 1); }
    __builtin_amdgcn_s_barrier();
    wait_lgkm0();
    __builtin_amdgcn_s_setprio(1);
#pragma unroll
    for (int m = 0; m < 4; m++)
#pragma unroll
      for (int n = 2; n < 4; n++) {
        acc[m][n] = MFMA(fa[m][0], fb[n][0], acc[m][n]);
        acc[m][n] = MFMA(fa[m][1], fb[n][1], acc[m][n]);
      }
    __builtin_amdgcn_s_setprio(0);
    __builtin_amdgcn_s_barrier();
    // ---- ph3 ---- (B halves of buf b free after ph2 barrier)
#pragma unroll
    for (int m = 0; m < 4; m++) { fa[m][0] = LDA(b, 4 + m, 0); fa[m][1] = LDA(b, 4 + m, 1); }
    if (dostage) STAGE(b, 1, pB, kts);
    __builtin_amdgcn_s_barrier();
    wait_lgkm0();
    __builtin_amdgcn_s_setprio(1);
#pragma unroll
    for (int m = 0; m < 4; m++)
#pragma unroll
      for (int n = 0; n < 2; n++) {
        acc[4 + m][n] = MFMA(fa[m][0], fb[n][0], acc[4 + m][n]);
        acc[4 + m][n] = MFMA(fa[m][1], fb[n][1], acc[4 + m][n]);
      }
    __builtin_amdgcn_s_setprio(0);
    __builtin_amdgcn_s_barrier();
    // ---- ph4 ---- (A halves of buf b free after ph3 barrier)
    if (dostage) STAGE(b, 0, pA, kts);
    if (vm == 8) wait_vm8();
    else if (vm == 0) wait_vm0();
    __builtin_amdgcn_s_barrier();
    __builtin_amdgcn_s_setprio(1);
#pragma unroll
    for (int m = 0; m < 4; m++)
#pragma unroll
      for (int n = 2; n < 4; n++) {
        acc[4 + m][n] = MFMA(fa[m][0], fb[n][0], acc[4 + m][n]);
        acc[4 + m][n] = MFMA(fa[m][1], fb[n][1], acc[4 + m][n]);
      }
    __builtin_amdgcn_s_setprio(0);
    __builtin_amdgcn_s_barrier();
  };

  // ---- prologue: stage tiles 0 (buf0) and 1 (buf1) ----
  int NT = KLEN / 64;
  STAGE(0, 1, pB, 0); STAGE(0, 0, pA, 0);
  STAGE(1, 1, pB, 1); STAGE(1, 0, pA, 1);
  wait_vm8();
  __builtin_amdgcn_s_barrier();

  int NIT = NT / 2;
  for (int it = 0; it < NIT - 1; ++it) {
    TILE(0, 2 * it + 2, true, 8);
    TILE(1, 2 * it + 3, true, 8);
  }
  TILE(0, 0, false, 0);
  TILE(1, 0, false, -1);

  // ---- epilogue ----
  int lr = (l >> 4) * 4, lc = l & 15;
#pragma unroll
  for (int m = 0; m < 8; m++) {
    int rbase = wr * 128 + m * 16 + lr;
#pragma unroll
    for (int j = 0; j < 4; j++) {
      int r = rbase + j;
      if (r < nrows) {
        if constexpr (MODE == 0) {
          size_t gb = (size_t)(row0 + r) * FC + by * 128 + wc * 32 + lc;
#pragma unroll
          for (int n = 0; n < 2; n++) {
            float g = acc[m][n][j], u = acc[m][n + 2][j];
            float sv = g / (1.0f + __expf(-g));
            G[gb + n * 16] = f2bf(sv * u);
          }
        } else if constexpr (MODE == 2) {
          float w = roww[row0 + r];
          int tok = rowtok[row0 + r];
          size_t ob = (size_t)tok * D_HID + by * 256 + wc * 64 + lc;
#pragma unroll
          for (int n = 0; n < 4; n++) atomicAdd(&out[ob + n * 16], acc[m][n][j] * w);
        } else {  // MODE 3: plain store to P[kz][row0+r][...]
          float w = roww[row0 + r];
          size_t pb = ((size_t)kz * NT2 + (row0 + r)) * D_HID + by * 256 + wc * 64 + lc;
#pragma unroll
          for (int n = 0; n < 4; n++) out[pb + n * 16] = acc[m][n][j] * w;
        }
      }
    }
  }
#undef LDA
#undef LDB
}

extern "C" void kernel_launch(void* const* d_in, const int* in_sizes, int n_in,
                              void* d_out, int out_size, void* d_ws, size_t ws_size,
                              hipStream_t stream) {
  (void)in_sizes; (void)n_in;
  const float* h  = (const float*)d_in[0];
  const float* rw = (const float*)d_in[1];
  const float* gw = (const float*)d_in[2];
  const float* uw = (const float*)d_in[3];
  const float* dw = (const float*)d_in[4];
  float* out = (float*)d_out;

  char* base = (char*)d_ws;
  size_t off = 0;
  auto alloc = [&](size_t b) -> char* {
    char* r = base + off;
    off += (b + 255) & ~(size_t)255;
    return r;
  };

  u16*   hb     = (u16*)alloc((size_t)T_TOK * D_HID * 2);
  int*   cntB   = (int*)alloc(NEXP * CBANKS * 4);
  float* psumB  = (float*)alloc(NEXP * CBANKS * 4);
  int*   offs   = (int*)alloc((NEXP + 1) * 4);
  int*   cnt2   = (int*)alloc(NEXP * 4);
  int*   meta   = (int*)alloc(64);
  int4*  tiles  = (int4*)alloc(NTIL * sizeof(int4));
  int*   topk_e = (int*)alloc(T_TOK * 4);
  float* topk_w = (float*)alloc((size_t)T_TOK * 2 * 4);
  int*   rowtok = (int*)alloc(NT2 * 4);
  float* roww   = (float*)alloc(NT2 * 4);
  int*   invmap = (int*)alloc(NT2 * 4);

  size_t zbytes = (size_t)((char*)topk_e - (char*)cntB);

  const size_t GROWS = NT2 + (size_t)BMR * NEXP;   // 18432 padded rows
  const size_t EDF = (size_t)NEXP * D_HID * F_INT;
  size_t avail = (ws_size > off) ? ws_size - off : 0;
  auto need = [&](int nc) -> size_t {
    return 3 * EDF * 2 + GROWS * (size_t)(F_INT / nc) * 2 + 65536;
  };
  int nchunk = 4;
  if      (avail >= need(1)) nchunk = 1;
  else if (avail >= need(2)) nchunk = 2;
  u16* gT = (u16*)alloc(EDF * 2);
  u16* uT = (u16*)alloc(EDF * 2);
  u16* dT = (u16*)alloc(EDF * 2);
  int FC = F_INT / nchunk;
  u16* G = (u16*)alloc(GROWS * (size_t)FC * 2);

  hipMemsetAsync(cntB, 0, zbytes, stream);
  if (nchunk != 1) hipMemsetAsync(d_out, 0, (size_t)out_size * 4, stream);

  k_router<<<T_TOK / 4, 256, 0, stream>>>(h, rw, hb, cntB, psumB, topk_e, topk_w);
  k_scan<<<1, 64, 0, stream>>>(cntB, psumB, offs, tiles, meta, out + (out_size - 1), cnt2);
  k_scatter<<<T_TOK / 256, 256, 0, stream>>>(topk_e, topk_w, offs, cnt2, rowtok, roww, invmap);
  k_cvt_all<<<24576, 256, 0, stream>>>(gw, uw, dw, gT, uT, dT);

  if (nchunk == 1) {
    // P[2][NT2][1024] f32 (134217728 B) aliases gT..uT (dead after gateup).
    float* P = (float*)gT;
    dim3 g1(NTIL, F_INT / 128, 1);
    dim3 g2(NTIL * 4, 1, 2);                  // packed (tile,by), XCD-chunked
    k_mm8<0><<<g1, 512, 0, stream>>>(hb, gT, uT, tiles, meta, rowtok, roww, G, out,
                                     0, F_INT, D_HID);
    k_mm8<3><<<g2, 512, 0, stream>>>(G, dT, dT, tiles, meta, rowtok, roww, G, P,
                                     0, F_INT, F_INT / 2);
    k_combine<<<T_TOK, 256, 0, stream>>>(P, invmap, out);
  } else {
    for (int c = 0; c < nchunk; c++) {
      int fcb = c * FC;
      dim3 g1(NTIL, FC / 128, 1);
      dim3 g2(NTIL, D_HID / 256, 2);
      k_mm8<0><<<g1, 512, 0, stream>>>(hb, gT, uT, tiles, meta, rowtok, roww, G, out,
                                       fcb, FC, D_HID);
      k_mm8<2><<<g2, 512, 0, stream>>>(G, dT, dT, tiles, meta, rowtok, roww, G, out,
                                       fcb, FC, FC / 2);
    }
  }
}